// Round 6
// baseline (266.720 us; speedup 1.0000x reference)
//
#include <hip/hip_runtime.h>
#include <math.h>

// nodes-per-bucket = 128 (pow2). nbk = ceil(N/128) buckets (<= 512 for N<=65536).
#define NPB_SHIFT 7
#define NPB 128
#define NBK_MAX 512

// ---------------- CSR build ----------------

__global__ void k_init_counts(int* counts, int n) {
  int i = blockIdx.x * blockDim.x + threadIdx.x;
  if (i < n) counts[i] = 1;  // self-loop
}

__global__ void k_hist(const int* __restrict__ dst, int E, int* counts) {
  int stride = gridDim.x * blockDim.x;
  for (int e = blockIdx.x * blockDim.x + threadIdx.x; e < E; e += stride)
    atomicAdd(&counts[dst[e]], 1);
}

__global__ void k_scan_block(const int* __restrict__ in, int* __restrict__ out,
                             int* __restrict__ sums, int n) {
  __shared__ int tmp[1024];
  int tid = threadIdx.x;
  int i = blockIdx.x * 1024 + tid;
  int v = (i < n) ? in[i] : 0;
  int x = v;
  tmp[tid] = x;
  __syncthreads();
  for (int off = 1; off < 1024; off <<= 1) {
    int y = (tid >= off) ? tmp[tid - off] : 0;
    __syncthreads();
    x += y;
    tmp[tid] = x;
    __syncthreads();
  }
  if (i < n) out[i] = x - v;             // exclusive within block
  if (tid == 1023) sums[blockIdx.x] = x; // block total
}

__global__ void k_scan_sums(int* sums, int nb) {
  if (blockIdx.x == 0 && threadIdx.x == 0) {
    int run = 0;
    for (int i = 0; i < nb; i++) { int v = sums[i]; sums[i] = run; run += v; }
  }
}

__global__ void k_add_back(int* __restrict__ row_ptr, const int* __restrict__ sums,
                           int n, int total) {
  int i = blockIdx.x * blockDim.x + threadIdx.x;
  if (i < n) row_ptr[i] += sums[i >> 10];
  if (i == 0) row_ptr[n] = total;
}

// bucket offsets derived from row_ptr: edges-only prefix = row_ptr[node] - node
__global__ void k_bucket_offsets(const int* __restrict__ row_ptr,
                                 int* __restrict__ boff, int* __restrict__ bcur,
                                 int nbk, int N) {
  int i = blockIdx.x * blockDim.x + threadIdx.x;
  if (i <= nbk) {
    int node = min(i << NPB_SHIFT, N);
    int v = row_ptr[node] - node;
    boff[i] = v;
    if (i < nbk) bcur[i] = v;
  }
}

// P1: LDS-aggregated bucket scatter.
__global__ __launch_bounds__(256) void k_scatter_agg(
    const int* __restrict__ src, const int* __restrict__ dst,
    const float* __restrict__ ea, int E, int nbk, int chunk,
    int* bcur, int2* __restrict__ tmp) {
  __shared__ int lcnt[NBK_MAX], lcnt2[NBK_MAX], lbase[NBK_MAX];
  int t = threadIdx.x;
  for (int i = t; i < nbk; i += 256) { lcnt[i] = 0; lcnt2[i] = 0; }
  __syncthreads();
  int c0 = blockIdx.x * chunk;
  int c1 = min(E, c0 + chunk);
  for (int e = c0 + t; e < c1; e += 256)
    atomicAdd(&lcnt[dst[e] >> NPB_SHIFT], 1);
  __syncthreads();
  for (int i = t; i < nbk; i += 256) {
    int c = lcnt[i];
    lbase[i] = c ? atomicAdd(&bcur[i], c) : 0;
  }
  __syncthreads();
  for (int e = c0 + t; e < c1; e += 256) {
    int d = dst[e];
    int b = d >> NPB_SHIFT;
    int pos = lbase[b] + atomicAdd(&lcnt2[b], 1);
    tmp[pos] = make_int2(((d & (NPB - 1)) << 20) | src[e], __float_as_int(ea[e]));
  }
}

// P2: one block per bucket; self-loops + bucket edges -> contiguous eidx window.
__global__ __launch_bounds__(256) void k_bucket_to_csr(
    const int2* __restrict__ tmp, const int* __restrict__ boff,
    const int* __restrict__ row_ptr, int N, int2* __restrict__ eidx) {
  __shared__ int cur[NPB];
  int b = blockIdx.x;
  int n0 = b << NPB_SHIFT;
  int nn = min(NPB, N - n0);
  int t = threadIdx.x;
  if (t < nn) {
    int node = n0 + t;
    int rp = row_ptr[node];
    eidx[rp] = make_int2(node, __float_as_int(1.0f));  // self loop
    cur[t] = rp + 1;
  }
  __syncthreads();
  int i1 = boff[b + 1];
  for (int i = boff[b] + t; i < i1; i += 256) {
    int2 r = tmp[i];
    int pos = atomicAdd(&cur[(r.x >> 20) & (NPB - 1)], 1);
    eidx[pos] = make_int2(r.x & 0xFFFFF, r.y);
  }
}

// ---------------- node linear (LDS-tiled GEMM): [xl|xr] = h @ [Wl|Wr] + [bl|br]

template<int CIN>
__global__ __launch_bounds__(256) void k_lin2_tiled(
    const float* __restrict__ h,
    const float* __restrict__ Wl, const float* __restrict__ bl,
    const float* __restrict__ Wr, const float* __restrict__ br,
    float* __restrict__ xl, float* __restrict__ xr, int N) {
  __shared__ float sW[64][128];  // 32 KB
  __shared__ float sH[64][64];   // 16 KB
  const int t = threadIdx.x;
  const int row0 = blockIdx.x * 64;
  const int c4 = (t & 31) * 4;
  const int rr = (t >> 5) * 8;

  float acc[8][4];
  #pragma unroll
  for (int r = 0; r < 8; r++)
    #pragma unroll
    for (int c = 0; c < 4; c++) acc[r][c] = 0.f;

  for (int kt = 0; kt < CIN; kt += 64) {
    __syncthreads();
    #pragma unroll
    for (int i = 0; i < 8; i++) {
      int flat = i * 1024 + t * 4;
      int k = flat >> 7, j = flat & 127;
      const float* Wsrc = (j < 64) ? Wl : Wr;
      *(float4*)&sW[k][j] = *(const float4*)&Wsrc[(size_t)(kt + k) * 64 + (j & 63)];
    }
    #pragma unroll
    for (int i = 0; i < 4; i++) {
      int flat = i * 1024 + t * 4;
      int r = flat >> 6, k = flat & 63;
      float4 v = make_float4(0.f, 0.f, 0.f, 0.f);
      if (row0 + r < N) v = *(const float4*)&h[(size_t)(row0 + r) * CIN + kt + k];
      *(float4*)&sH[r][k] = v;
    }
    __syncthreads();
    #pragma unroll 8
    for (int k = 0; k < 64; k++) {
      float4 w = *(float4*)&sW[k][c4];
      #pragma unroll
      for (int r = 0; r < 8; r++) {
        float hv = sH[rr + r][k];
        acc[r][0] = fmaf(hv, w.x, acc[r][0]);
        acc[r][1] = fmaf(hv, w.y, acc[r][1]);
        acc[r][2] = fmaf(hv, w.z, acc[r][2]);
        acc[r][3] = fmaf(hv, w.w, acc[r][3]);
      }
    }
  }

  const float* bsrc = (c4 < 64) ? bl : br;
  float bv[4];
  #pragma unroll
  for (int c = 0; c < 4; c++) bv[c] = bsrc[(c4 & 63) + c];
  float* o = (c4 < 64) ? xl : xr;
  #pragma unroll
  for (int r = 0; r < 8; r++) {
    int row = row0 + rr + r;
    if (row < N) {
      float4 v = make_float4(acc[r][0] + bv[0], acc[r][1] + bv[1],
                             acc[r][2] + bv[2], acc[r][3] + bv[3]);
      *(float4*)&o[(size_t)row * 64 + (c4 & 63)] = v;
    }
  }
}

// ---------------- per-dst-node edge pass ----------------
// 8 groups per wave (8 lanes x 8 channels). Group g processes edges
// e0+g, e0+g+8, ... with its own online (m,s,acc) deferred-max softmax state;
// 1-deep prefetch per group -> high memory-level parallelism.
// States merged across groups at the end via shfl_xor 8/16/32.

#define RESCALE_THR 8.0f

__global__ __launch_bounds__(256) void k_gat_edge(
    const float* __restrict__ xl, const float* __restrict__ xr,
    const int* __restrict__ row_ptr, const int2* __restrict__ eidx,
    const float* __restrict__ We, const float* __restrict__ att,
    const float* __restrict__ bias,
    float* __restrict__ out, int N) {
  int n = (blockIdx.x * blockDim.x + threadIdx.x) >> 6;  // one wave per node
  if (n >= N) return;
  int lane = threadIdx.x & 63;
  int g = lane >> 3;          // 8 groups/wave
  int cb = (lane & 7) * 8;    // 8 channels per lane

  const float* xrp = &xr[(size_t)n * 64 + cb];
  float4 xiA = *(const float4*)xrp;
  float4 xiB = *(const float4*)(xrp + 4);
  float4 weA = *(const float4*)&We[cb];
  float4 weB = *(const float4*)&We[cb + 4];
  float4 atA = *(const float4*)&att[cb];
  float4 atB = *(const float4*)&att[cb + 4];

  int e0 = row_ptr[n], e1 = row_ptr[n + 1];

  float m = -INFINITY, s = 0.f;
  float4 accA = make_float4(0.f, 0.f, 0.f, 0.f);
  float4 accB = make_float4(0.f, 0.f, 0.f, 0.f);

  int e = e0 + g;
  int2 meta = make_int2(0, 0);
  float4 xjA = make_float4(0.f, 0.f, 0.f, 0.f);
  float4 xjB = make_float4(0.f, 0.f, 0.f, 0.f);
  if (e < e1) {
    meta = eidx[e];
    const float* p = &xl[(size_t)meta.x * 64 + cb];
    xjA = *(const float4*)p;
    xjB = *(const float4*)(p + 4);
  }

  while (e < e1) {
    int2 cm = meta;
    float4 cxA = xjA, cxB = xjB;
    int en = e + 8;
    if (en < e1) {  // prefetch next edge for this group
      meta = eidx[en];
      const float* p = &xl[(size_t)meta.x * 64 + cb];
      xjA = *(const float4*)p;
      xjB = *(const float4*)(p + 4);
    }
    float eav = __int_as_float(cm.y);
    float4 zA, zB;
    zA.x = xiA.x + cxA.x + eav * weA.x;
    zA.y = xiA.y + cxA.y + eav * weA.y;
    zA.z = xiA.z + cxA.z + eav * weA.z;
    zA.w = xiA.w + cxA.w + eav * weA.w;
    zB.x = xiB.x + cxB.x + eav * weB.x;
    zB.y = xiB.y + cxB.y + eav * weB.y;
    zB.z = xiB.z + cxB.z + eav * weB.z;
    zB.w = xiB.w + cxB.w + eav * weB.w;
    zA.x = fmaxf(zA.x, 0.f) + 0.2f * fminf(zA.x, 0.f);
    zA.y = fmaxf(zA.y, 0.f) + 0.2f * fminf(zA.y, 0.f);
    zA.z = fmaxf(zA.z, 0.f) + 0.2f * fminf(zA.z, 0.f);
    zA.w = fmaxf(zA.w, 0.f) + 0.2f * fminf(zA.w, 0.f);
    zB.x = fmaxf(zB.x, 0.f) + 0.2f * fminf(zB.x, 0.f);
    zB.y = fmaxf(zB.y, 0.f) + 0.2f * fminf(zB.y, 0.f);
    zB.z = fmaxf(zB.z, 0.f) + 0.2f * fminf(zB.z, 0.f);
    zB.w = fmaxf(zB.w, 0.f) + 0.2f * fminf(zB.w, 0.f);
    float p = zA.x * atA.x + zA.y * atA.y + zA.z * atA.z + zA.w * atA.w
            + zB.x * atB.x + zB.y * atB.y + zB.z * atB.z + zB.w * atB.w;
    // reduce over the 8 lanes of this group (DPP-friendly small offsets)
    #pragma unroll
    for (int off = 1; off < 8; off <<= 1) p += __shfl_xor(p, off, 64);
    // deferred-max online softmax (group-uniform branch; rescale is rare)
    if (p > m + RESCALE_THR) {
      float coef = __expf(m - p);  // 0 on first edge (m=-inf)
      s = fmaf(s, coef, 1.f);
      accA.x = fmaf(accA.x, coef, cxA.x);
      accA.y = fmaf(accA.y, coef, cxA.y);
      accA.z = fmaf(accA.z, coef, cxA.z);
      accA.w = fmaf(accA.w, coef, cxA.w);
      accB.x = fmaf(accB.x, coef, cxB.x);
      accB.y = fmaf(accB.y, coef, cxB.y);
      accB.z = fmaf(accB.z, coef, cxB.z);
      accB.w = fmaf(accB.w, coef, cxB.w);
      m = p;
    } else {
      float wgt = __expf(p - m);   // bounded by e^THR
      s += wgt;
      accA.x = fmaf(wgt, cxA.x, accA.x);
      accA.y = fmaf(wgt, cxA.y, accA.y);
      accA.z = fmaf(wgt, cxA.z, accA.z);
      accA.w = fmaf(wgt, cxA.w, accA.w);
      accB.x = fmaf(wgt, cxB.x, accB.x);
      accB.y = fmaf(wgt, cxB.y, accB.y);
      accB.z = fmaf(wgt, cxB.z, accB.z);
      accB.w = fmaf(wgt, cxB.w, accB.w);
    }
    e = en;
  }

  // merge the 8 group states (lane^8/16/32 hold same channels)
  #pragma unroll
  for (int off = 8; off <= 32; off <<= 1) {
    float mo = __shfl_xor(m, off, 64);
    float so = __shfl_xor(s, off, 64);
    float4 aoA, aoB;
    aoA.x = __shfl_xor(accA.x, off, 64);
    aoA.y = __shfl_xor(accA.y, off, 64);
    aoA.z = __shfl_xor(accA.z, off, 64);
    aoA.w = __shfl_xor(accA.w, off, 64);
    aoB.x = __shfl_xor(accB.x, off, 64);
    aoB.y = __shfl_xor(accB.y, off, 64);
    aoB.z = __shfl_xor(accB.z, off, 64);
    aoB.w = __shfl_xor(accB.w, off, 64);
    float mn = fmaxf(m, mo);
    float cs = (m == -INFINITY) ? 0.f : __expf(m - mn);
    float co = (mo == -INFINITY) ? 0.f : __expf(mo - mn);
    s = s * cs + so * co;
    accA.x = accA.x * cs + aoA.x * co;
    accA.y = accA.y * cs + aoA.y * co;
    accA.z = accA.z * cs + aoA.z * co;
    accA.w = accA.w * cs + aoA.w * co;
    accB.x = accB.x * cs + aoB.x * co;
    accB.y = accB.y * cs + aoB.y * co;
    accB.z = accB.z * cs + aoB.z * co;
    accB.w = accB.w * cs + aoB.w * co;
    m = mn;
  }

  if (g == 0) {  // lanes 0..7 hold the merged state: 8 lanes x 32 B = full row
    float inv = 1.0f / s;
    float4 oA, oB;
    oA.x = accA.x * inv + bias[cb + 0];
    oA.y = accA.y * inv + bias[cb + 1];
    oA.z = accA.z * inv + bias[cb + 2];
    oA.w = accA.w * inv + bias[cb + 3];
    oB.x = accB.x * inv + bias[cb + 4];
    oB.y = accB.y * inv + bias[cb + 5];
    oB.z = accB.z * inv + bias[cb + 6];
    oB.w = accB.w * inv + bias[cb + 7];
    float* op = &out[(size_t)n * 64 + cb];
    *(float4*)op = oA;
    *(float4*)(op + 4) = oB;
  }
}

// ---------------- launch ----------------

extern "C" void kernel_launch(void* const* d_in, const int* in_sizes, int n_in,
                              void* d_out, int out_size, void* d_ws, size_t ws_size,
                              hipStream_t stream) {
  const float* x    = (const float*)d_in[0];
  const int*   ei   = (const int*)d_in[1];
  const float* ea   = (const float*)d_in[2];
  const float* Wl0  = (const float*)d_in[3];
  const float* bl0  = (const float*)d_in[4];
  const float* Wr0  = (const float*)d_in[5];
  const float* br0  = (const float*)d_in[6];
  const float* We0  = (const float*)d_in[7];
  const float* att0 = (const float*)d_in[8];
  const float* bias0= (const float*)d_in[9];
  const float* Wl1  = (const float*)d_in[10];
  const float* bl1  = (const float*)d_in[11];
  const float* Wr1  = (const float*)d_in[12];
  const float* br1  = (const float*)d_in[13];
  const float* We1  = (const float*)d_in[14];
  const float* att1 = (const float*)d_in[15];
  const float* bias1= (const float*)d_in[16];

  const int N  = in_sizes[0] / 128;
  const int E  = in_sizes[1] / 2;
  const int ET = E + N;
  const int* src = ei;
  const int* dst = ei + E;
  const int nbk = (N + NPB - 1) >> NPB_SHIFT;

  char* w = (char*)d_ws;
  float* xl      = (float*)w; w += (size_t)N * 64 * 4;
  float* xr      = (float*)w; w += (size_t)N * 64 * 4;
  float* h1      = (float*)w; w += (size_t)N * 64 * 4;
  int*   row_ptr = (int*)w;   w += (size_t)(N + 2) * 4;
  int2*  eidx    = (int2*)w;  w += (size_t)ET * 8;
  int*   sums    = (int*)w;   w += 256;
  int*   boff    = (int*)w;   w += (NBK_MAX + 1) * 4;
  int*   bcur    = (int*)w;   w += NBK_MAX * 4;
  int2*  tmp     = (int2*)xl;  // aliases xl: CSR build precedes layer-0 lin2

  float* out = (float*)d_out;

  // ---- CSR build (same graph for both layers) ----
  int nb_scan = (N + 1023) / 1024;
  k_init_counts<<<(N + 255) / 256, 256, 0, stream>>>(row_ptr, N);
  k_hist<<<1024, 256, 0, stream>>>(dst, E, row_ptr);
  k_scan_block<<<nb_scan, 1024, 0, stream>>>(row_ptr, row_ptr, sums, N);
  k_scan_sums<<<1, 64, 0, stream>>>(sums, nb_scan);
  k_add_back<<<(N + 255) / 256, 256, 0, stream>>>(row_ptr, sums, N, ET);
  k_bucket_offsets<<<(nbk + 256) / 256, 256, 0, stream>>>(row_ptr, boff, bcur, nbk, N);
  {
    int nblk = 128;
    int chunk = (E + nblk - 1) / nblk;
    k_scatter_agg<<<nblk, 256, 0, stream>>>(src, dst, ea, E, nbk, chunk, bcur, tmp);
  }
  k_bucket_to_csr<<<nbk, 256, 0, stream>>>(tmp, boff, row_ptr, N, eidx);

  // ---- layer 0: 128 -> 64 ----
  {
    int nblk = (N + 63) / 64;
    k_lin2_tiled<128><<<nblk, 256, 0, stream>>>(x, Wl0, bl0, Wr0, br0, xl, xr, N);
    k_gat_edge<<<(N + 3) / 4, 256, 0, stream>>>(xl, xr, row_ptr, eidx, We0, att0, bias0, h1, N);
  }
  // ---- layer 1: 64 -> 64 ----
  {
    int nblk = (N + 63) / 64;
    k_lin2_tiled<64><<<nblk, 256, 0, stream>>>(h1, Wl1, bl1, Wr1, br1, xl, xr, N);
    k_gat_edge<<<(N + 3) / 4, 256, 0, stream>>>(xl, xr, row_ptr, eidx, We1, att1, bias1, out, N);
  }
}

// Round 7
// 257.111 us; speedup vs baseline: 1.0374x; 1.0374x over previous
//
#include <hip/hip_runtime.h>
#include <hip/hip_fp16.h>
#include <math.h>

// nodes-per-bucket = 128 (pow2). nbk = ceil(N/128) buckets (<= 512 for N<=65536).
#define NPB_SHIFT 7
#define NPB 128
#define NBK_MAX 512

// ---------------- CSR build ----------------

__global__ void k_init_counts(int* counts, int n) {
  int i = blockIdx.x * blockDim.x + threadIdx.x;
  if (i < n) counts[i] = 1;  // self-loop
}

__global__ void k_hist(const int* __restrict__ dst, int E, int* counts) {
  int stride = gridDim.x * blockDim.x;
  for (int e = blockIdx.x * blockDim.x + threadIdx.x; e < E; e += stride)
    atomicAdd(&counts[dst[e]], 1);
}

__global__ void k_scan_block(const int* __restrict__ in, int* __restrict__ out,
                             int* __restrict__ sums, int n) {
  __shared__ int tmp[1024];
  int tid = threadIdx.x;
  int i = blockIdx.x * 1024 + tid;
  int v = (i < n) ? in[i] : 0;
  int x = v;
  tmp[tid] = x;
  __syncthreads();
  for (int off = 1; off < 1024; off <<= 1) {
    int y = (tid >= off) ? tmp[tid - off] : 0;
    __syncthreads();
    x += y;
    tmp[tid] = x;
    __syncthreads();
  }
  if (i < n) out[i] = x - v;             // exclusive within block
  if (tid == 1023) sums[blockIdx.x] = x; // block total
}

__global__ void k_scan_sums(int* sums, int nb) {
  if (blockIdx.x == 0 && threadIdx.x == 0) {
    int run = 0;
    for (int i = 0; i < nb; i++) { int v = sums[i]; sums[i] = run; run += v; }
  }
}

__global__ void k_add_back(int* __restrict__ row_ptr, const int* __restrict__ sums,
                           int n, int total) {
  int i = blockIdx.x * blockDim.x + threadIdx.x;
  if (i < n) row_ptr[i] += sums[i >> 10];
  if (i == 0) row_ptr[n] = total;
}

// bucket offsets derived from row_ptr: edges-only prefix = row_ptr[node] - node
__global__ void k_bucket_offsets(const int* __restrict__ row_ptr,
                                 int* __restrict__ boff, int* __restrict__ bcur,
                                 int nbk, int N) {
  int i = blockIdx.x * blockDim.x + threadIdx.x;
  if (i <= nbk) {
    int node = min(i << NPB_SHIFT, N);
    int v = row_ptr[node] - node;
    boff[i] = v;
    if (i < nbk) bcur[i] = v;
  }
}

// P1: LDS-aggregated bucket scatter.
__global__ __launch_bounds__(256) void k_scatter_agg(
    const int* __restrict__ src, const int* __restrict__ dst,
    const float* __restrict__ ea, int E, int nbk, int chunk,
    int* bcur, int2* __restrict__ tmp) {
  __shared__ int lcnt[NBK_MAX], lcnt2[NBK_MAX], lbase[NBK_MAX];
  int t = threadIdx.x;
  for (int i = t; i < nbk; i += 256) { lcnt[i] = 0; lcnt2[i] = 0; }
  __syncthreads();
  int c0 = blockIdx.x * chunk;
  int c1 = min(E, c0 + chunk);
  for (int e = c0 + t; e < c1; e += 256)
    atomicAdd(&lcnt[dst[e] >> NPB_SHIFT], 1);
  __syncthreads();
  for (int i = t; i < nbk; i += 256) {
    int c = lcnt[i];
    lbase[i] = c ? atomicAdd(&bcur[i], c) : 0;
  }
  __syncthreads();
  for (int e = c0 + t; e < c1; e += 256) {
    int d = dst[e];
    int b = d >> NPB_SHIFT;
    int pos = lbase[b] + atomicAdd(&lcnt2[b], 1);
    tmp[pos] = make_int2(((d & (NPB - 1)) << 20) | src[e], __float_as_int(ea[e]));
  }
}

// P2: one block per bucket; self-loops + bucket edges -> contiguous eidx window.
__global__ __launch_bounds__(256) void k_bucket_to_csr(
    const int2* __restrict__ tmp, const int* __restrict__ boff,
    const int* __restrict__ row_ptr, int N, int2* __restrict__ eidx) {
  __shared__ int cur[NPB];
  int b = blockIdx.x;
  int n0 = b << NPB_SHIFT;
  int nn = min(NPB, N - n0);
  int t = threadIdx.x;
  if (t < nn) {
    int node = n0 + t;
    int rp = row_ptr[node];
    eidx[rp] = make_int2(node, __float_as_int(1.0f));  // self loop
    cur[t] = rp + 1;
  }
  __syncthreads();
  int i1 = boff[b + 1];
  for (int i = boff[b] + t; i < i1; i += 256) {
    int2 r = tmp[i];
    int pos = atomicAdd(&cur[(r.x >> 20) & (NPB - 1)], 1);
    eidx[pos] = make_int2(r.x & 0xFFFFF, r.y);
  }
}

// ---------------- node linear (LDS-tiled GEMM) ----------------
// [xl|xr] = h @ [Wl|Wr] + [bl|br]; xl stored as fp16 (gather table), xr fp32.

template<int CIN>
__global__ __launch_bounds__(256) void k_lin2_tiled(
    const float* __restrict__ h,
    const float* __restrict__ Wl, const float* __restrict__ bl,
    const float* __restrict__ Wr, const float* __restrict__ br,
    __half* __restrict__ xlh, float* __restrict__ xr, int N) {
  __shared__ float sW[64][128];  // 32 KB
  __shared__ float sH[64][64];   // 16 KB
  const int t = threadIdx.x;
  const int row0 = blockIdx.x * 64;
  const int c4 = (t & 31) * 4;
  const int rr = (t >> 5) * 8;

  float acc[8][4];
  #pragma unroll
  for (int r = 0; r < 8; r++)
    #pragma unroll
    for (int c = 0; c < 4; c++) acc[r][c] = 0.f;

  for (int kt = 0; kt < CIN; kt += 64) {
    __syncthreads();
    #pragma unroll
    for (int i = 0; i < 8; i++) {
      int flat = i * 1024 + t * 4;
      int k = flat >> 7, j = flat & 127;
      const float* Wsrc = (j < 64) ? Wl : Wr;
      *(float4*)&sW[k][j] = *(const float4*)&Wsrc[(size_t)(kt + k) * 64 + (j & 63)];
    }
    #pragma unroll
    for (int i = 0; i < 4; i++) {
      int flat = i * 1024 + t * 4;
      int r = flat >> 6, k = flat & 63;
      float4 v = make_float4(0.f, 0.f, 0.f, 0.f);
      if (row0 + r < N) v = *(const float4*)&h[(size_t)(row0 + r) * CIN + kt + k];
      *(float4*)&sH[r][k] = v;
    }
    __syncthreads();
    #pragma unroll 8
    for (int k = 0; k < 64; k++) {
      float4 w = *(float4*)&sW[k][c4];
      #pragma unroll
      for (int r = 0; r < 8; r++) {
        float hv = sH[rr + r][k];
        acc[r][0] = fmaf(hv, w.x, acc[r][0]);
        acc[r][1] = fmaf(hv, w.y, acc[r][1]);
        acc[r][2] = fmaf(hv, w.z, acc[r][2]);
        acc[r][3] = fmaf(hv, w.w, acc[r][3]);
      }
    }
  }

  const float* bsrc = (c4 < 64) ? bl : br;
  float bv[4];
  #pragma unroll
  for (int c = 0; c < 4; c++) bv[c] = bsrc[(c4 & 63) + c];
  #pragma unroll
  for (int r = 0; r < 8; r++) {
    int row = row0 + rr + r;
    if (row < N) {
      float v0 = acc[r][0] + bv[0], v1 = acc[r][1] + bv[1];
      float v2 = acc[r][2] + bv[2], v3 = acc[r][3] + bv[3];
      if (c4 < 64) {
        __half2 ha = __halves2half2(__float2half_rn(v0), __float2half_rn(v1));
        __half2 hb = __halves2half2(__float2half_rn(v2), __float2half_rn(v3));
        uint2 u;
        u.x = *(unsigned int*)&ha;
        u.y = *(unsigned int*)&hb;
        *(uint2*)&xlh[(size_t)row * 64 + c4] = u;
      } else {
        *(float4*)&xr[(size_t)row * 64 + (c4 & 63)] = make_float4(v0, v1, v2, v3);
      }
    }
  }
}

// ---------------- per-dst-node edge pass ----------------
// 4 groups per wave (16 lanes x 4 channels), fp16 gather, deferred-max
// online segment softmax. Group g processes edges e0+g, e0+g+4, ...;
// 1-deep prefetch; states merged across groups via shfl_xor 16/32.

#define RESCALE_THR 8.0f

__global__ __launch_bounds__(256) void k_gat_edge(
    const __half* __restrict__ xlh, const float* __restrict__ xr,
    const int* __restrict__ row_ptr, const int2* __restrict__ eidx,
    const float* __restrict__ We, const float* __restrict__ att,
    const float* __restrict__ bias,
    float* __restrict__ out, int N) {
  int n = (blockIdx.x * blockDim.x + threadIdx.x) >> 6;  // one wave per node
  if (n >= N) return;
  int lane = threadIdx.x & 63;
  int g = lane >> 4;
  int cb = (lane & 15) * 4;

  float4 xi = *(const float4*)&xr[(size_t)n * 64 + cb];
  float4 we = *(const float4*)&We[cb];
  float4 at = *(const float4*)&att[cb];

  int e0 = row_ptr[n], e1 = row_ptr[n + 1];

  float m = -INFINITY, s = 0.f;
  float4 acc = make_float4(0.f, 0.f, 0.f, 0.f);

  int e = e0 + g;
  int2 meta = make_int2(0, 0);
  uint2 raw = make_uint2(0, 0);
  if (e < e1) {
    meta = eidx[e];
    raw = *(const uint2*)&xlh[(size_t)meta.x * 64 + cb];
  }

  while (e < e1) {
    int2 cm = meta;
    uint2 craw = raw;
    int en = e + 4;
    if (en < e1) {  // prefetch next edge for this group
      meta = eidx[en];
      raw = *(const uint2*)&xlh[(size_t)meta.x * 64 + cb];
    }
    __half2 h01 = *(__half2*)&craw.x;
    __half2 h23 = *(__half2*)&craw.y;
    float x0 = __low2float(h01), x1 = __high2float(h01);
    float x2 = __low2float(h23), x3 = __high2float(h23);
    float eav = __int_as_float(cm.y);
    float z0 = xi.x + x0 + eav * we.x;
    float z1 = xi.y + x1 + eav * we.y;
    float z2 = xi.z + x2 + eav * we.z;
    float z3 = xi.w + x3 + eav * we.w;
    z0 = fmaxf(z0, 0.f) + 0.2f * fminf(z0, 0.f);
    z1 = fmaxf(z1, 0.f) + 0.2f * fminf(z1, 0.f);
    z2 = fmaxf(z2, 0.f) + 0.2f * fminf(z2, 0.f);
    z3 = fmaxf(z3, 0.f) + 0.2f * fminf(z3, 0.f);
    float p = z0 * at.x + z1 * at.y + z2 * at.z + z3 * at.w;
    #pragma unroll
    for (int off = 1; off < 16; off <<= 1) p += __shfl_xor(p, off, 64);
    // deferred-max online softmax: common path = 1 exp, no rescale
    if (p > m + RESCALE_THR) {
      float coef = __expf(m - p);  // 0 on first edge (m=-inf)
      s = fmaf(s, coef, 1.f);
      acc.x = fmaf(acc.x, coef, x0);
      acc.y = fmaf(acc.y, coef, x1);
      acc.z = fmaf(acc.z, coef, x2);
      acc.w = fmaf(acc.w, coef, x3);
      m = p;
    } else {
      float wgt = __expf(p - m);   // bounded by e^THR
      s += wgt;
      acc.x = fmaf(wgt, x0, acc.x);
      acc.y = fmaf(wgt, x1, acc.y);
      acc.z = fmaf(wgt, x2, acc.z);
      acc.w = fmaf(wgt, x3, acc.w);
    }
    e = en;
  }

  // merge the 4 group states (lane^16/32 hold same channels)
  #pragma unroll
  for (int off = 16; off <= 32; off <<= 1) {
    float mo = __shfl_xor(m, off, 64);
    float so = __shfl_xor(s, off, 64);
    float4 ao;
    ao.x = __shfl_xor(acc.x, off, 64);
    ao.y = __shfl_xor(acc.y, off, 64);
    ao.z = __shfl_xor(acc.z, off, 64);
    ao.w = __shfl_xor(acc.w, off, 64);
    float mn = fmaxf(m, mo);
    float cs = (m == -INFINITY) ? 0.f : __expf(m - mn);
    float co = (mo == -INFINITY) ? 0.f : __expf(mo - mn);
    s = s * cs + so * co;
    acc.x = acc.x * cs + ao.x * co;
    acc.y = acc.y * cs + ao.y * co;
    acc.z = acc.z * cs + ao.z * co;
    acc.w = acc.w * cs + ao.w * co;
    m = mn;
  }

  if (g == 0) {
    float inv = 1.0f / s;
    float4 o;
    o.x = acc.x * inv + bias[cb + 0];
    o.y = acc.y * inv + bias[cb + 1];
    o.z = acc.z * inv + bias[cb + 2];
    o.w = acc.w * inv + bias[cb + 3];
    *(float4*)&out[(size_t)n * 64 + cb] = o;
  }
}

// ---------------- launch ----------------

extern "C" void kernel_launch(void* const* d_in, const int* in_sizes, int n_in,
                              void* d_out, int out_size, void* d_ws, size_t ws_size,
                              hipStream_t stream) {
  const float* x    = (const float*)d_in[0];
  const int*   ei   = (const int*)d_in[1];
  const float* ea   = (const float*)d_in[2];
  const float* Wl0  = (const float*)d_in[3];
  const float* bl0  = (const float*)d_in[4];
  const float* Wr0  = (const float*)d_in[5];
  const float* br0  = (const float*)d_in[6];
  const float* We0  = (const float*)d_in[7];
  const float* att0 = (const float*)d_in[8];
  const float* bias0= (const float*)d_in[9];
  const float* Wl1  = (const float*)d_in[10];
  const float* bl1  = (const float*)d_in[11];
  const float* Wr1  = (const float*)d_in[12];
  const float* br1  = (const float*)d_in[13];
  const float* We1  = (const float*)d_in[14];
  const float* att1 = (const float*)d_in[15];
  const float* bias1= (const float*)d_in[16];

  const int N  = in_sizes[0] / 128;
  const int E  = in_sizes[1] / 2;
  const int ET = E + N;
  const int* src = ei;
  const int* dst = ei + E;
  const int nbk = (N + NPB - 1) >> NPB_SHIFT;

  char* w = (char*)d_ws;
  __half* xlh    = (__half*)w; w += (size_t)N * 64 * 2;   // fp16 gather table
  float*  xr     = (float*)w;  w += (size_t)N * 64 * 4;
  float*  h1     = (float*)w;  w += (size_t)N * 64 * 4;
  int*    row_ptr= (int*)w;    w += (size_t)(N + 2) * 4;
  int2*   eidx   = (int2*)w;   w += (size_t)ET * 8;
  int*    sums   = (int*)w;    w += 256;
  int*    boff   = (int*)w;    w += (NBK_MAX + 1) * 4;
  int*    bcur   = (int*)w;    w += NBK_MAX * 4;
  // tmp aliases xlh+xr (19.2 MB >= E*8): CSR build precedes layer-0 lin2
  int2*   tmp    = (int2*)xlh;

  float* out = (float*)d_out;

  // ---- CSR build (same graph for both layers) ----
  int nb_scan = (N + 1023) / 1024;
  k_init_counts<<<(N + 255) / 256, 256, 0, stream>>>(row_ptr, N);
  k_hist<<<1024, 256, 0, stream>>>(dst, E, row_ptr);
  k_scan_block<<<nb_scan, 1024, 0, stream>>>(row_ptr, row_ptr, sums, N);
  k_scan_sums<<<1, 64, 0, stream>>>(sums, nb_scan);
  k_add_back<<<(N + 255) / 256, 256, 0, stream>>>(row_ptr, sums, N, ET);
  k_bucket_offsets<<<(nbk + 256) / 256, 256, 0, stream>>>(row_ptr, boff, bcur, nbk, N);
  {
    int nblk = 128;
    int chunk = (E + nblk - 1) / nblk;
    k_scatter_agg<<<nblk, 256, 0, stream>>>(src, dst, ea, E, nbk, chunk, bcur, tmp);
  }
  k_bucket_to_csr<<<nbk, 256, 0, stream>>>(tmp, boff, row_ptr, N, eidx);

  // ---- layer 0: 128 -> 64 ----
  {
    int nblk = (N + 63) / 64;
    k_lin2_tiled<128><<<nblk, 256, 0, stream>>>(x, Wl0, bl0, Wr0, br0, xlh, xr, N);
    k_gat_edge<<<(N + 3) / 4, 256, 0, stream>>>(xlh, xr, row_ptr, eidx, We0, att0, bias0, h1, N);
  }
  // ---- layer 1: 64 -> 64 ----
  {
    int nblk = (N + 63) / 64;
    k_lin2_tiled<64><<<nblk, 256, 0, stream>>>(h1, Wl1, bl1, Wr1, br1, xlh, xr, N);
    k_gat_edge<<<(N + 3) / 4, 256, 0, stream>>>(xlh, xr, row_ptr, eidx, We1, att1, bias1, out, N);
  }
}

// Round 8
// 203.523 us; speedup vs baseline: 1.3105x; 1.2633x over previous
//
#include <hip/hip_runtime.h>
#include <hip/hip_fp16.h>
#include <math.h>

// nodes-per-bucket = 128 (pow2). nbk = ceil(N/128) buckets (<= 512 for N<=65536).
#define NPB_SHIFT 7
#define NPB 128
#define NBK_MAX 512

// ---------------- CSR build (bucket-local, no per-node global hist) --------

__global__ void k_zero(int* p, int n) {
  int i = blockIdx.x * blockDim.x + threadIdx.x;
  if (i < n) p[i] = 0;
}

// bucket histogram of dst (LDS-aggregated)
__global__ __launch_bounds__(256) void k_bhist(
    const int* __restrict__ dst, int E, int chunk, int nbk, int* bcount) {
  __shared__ int bh[NBK_MAX];
  int t = threadIdx.x;
  for (int i = t; i < nbk; i += 256) bh[i] = 0;
  __syncthreads();
  int c0 = blockIdx.x * chunk;
  int c1 = min(E, c0 + chunk);
  for (int e = c0 + t; e < c1; e += 256)
    atomicAdd(&bh[dst[e] >> NPB_SHIFT], 1);
  __syncthreads();
  for (int i = t; i < nbk; i += 256)
    if (bh[i]) atomicAdd(&bcount[i], bh[i]);
}

// exclusive scan of bucket counts (single block, 512 threads, Hillis-Steele)
__global__ __launch_bounds__(NBK_MAX) void k_scan_buckets(
    const int* __restrict__ bcount, int* __restrict__ boff,
    int* __restrict__ bcur, int nbk, int E) {
  __shared__ int tmp[NBK_MAX];
  int t = threadIdx.x;
  int v = (t < nbk) ? bcount[t] : 0;
  int x = v;
  tmp[t] = x;
  __syncthreads();
  for (int off = 1; off < NBK_MAX; off <<= 1) {
    int y = (t >= off) ? tmp[t - off] : 0;
    __syncthreads();
    x += y;
    tmp[t] = x;
    __syncthreads();
  }
  if (t < nbk) {
    int excl = x - v;
    boff[t] = excl;
    bcur[t] = excl;
  }
  if (t == nbk - 1) boff[nbk] = E;
}

// P1: LDS-aggregated bucket scatter (count chunk, reserve run, place).
__global__ __launch_bounds__(256) void k_scatter_agg(
    const int* __restrict__ src, const int* __restrict__ dst,
    const float* __restrict__ ea, int E, int nbk, int chunk,
    int* bcur, int2* __restrict__ tmp) {
  __shared__ int lcnt[NBK_MAX], lcnt2[NBK_MAX], lbase[NBK_MAX];
  int t = threadIdx.x;
  for (int i = t; i < nbk; i += 256) { lcnt[i] = 0; lcnt2[i] = 0; }
  __syncthreads();
  int c0 = blockIdx.x * chunk;
  int c1 = min(E, c0 + chunk);
  for (int e = c0 + t; e < c1; e += 256)
    atomicAdd(&lcnt[dst[e] >> NPB_SHIFT], 1);
  __syncthreads();
  for (int i = t; i < nbk; i += 256) {
    int c = lcnt[i];
    lbase[i] = c ? atomicAdd(&bcur[i], c) : 0;
  }
  __syncthreads();
  for (int e = c0 + t; e < c1; e += 256) {
    int d = dst[e];
    int b = d >> NPB_SHIFT;
    int pos = lbase[b] + atomicAdd(&lcnt2[b], 1);
    tmp[pos] = make_int2(((d & (NPB - 1)) << 20) | src[e], __float_as_int(ea[e]));
  }
}

// P2: one block per bucket. Count per-node in LDS, scan, build row_ptr,
// write self-loops + place edges into the bucket's contiguous eidx window.
__global__ __launch_bounds__(256) void k_bucket_to_csr(
    const int2* __restrict__ tmp, const int* __restrict__ boff,
    int N, int ET, int2* __restrict__ eidx, int* __restrict__ row_ptr) {
  __shared__ int cnt[NPB], sc[NPB], cur[NPB];
  int b = blockIdx.x;
  int n0 = b << NPB_SHIFT;
  int nn = min(NPB, N - n0);
  int t = threadIdx.x;
  if (t < NPB) cnt[t] = 0;
  __syncthreads();
  int i0 = boff[b], i1 = boff[b + 1];
  for (int i = i0 + t; i < i1; i += 256)
    atomicAdd(&cnt[(tmp[i].x >> 20) & (NPB - 1)], 1);
  __syncthreads();
  // exclusive scan over the NPB per-node counts (Hillis-Steele in LDS)
  int v = (t < NPB) ? cnt[t] : 0;
  int x = v;
  if (t < NPB) sc[t] = x;
  __syncthreads();
  for (int off = 1; off < NPB; off <<= 1) {
    int y = (t >= off && t < NPB) ? sc[t - off] : 0;
    __syncthreads();
    if (t < NPB) { x += y; sc[t] = x; }
    __syncthreads();
  }
  // eidx window for this bucket starts at boff[b] + n0 (n0 prior self-loops)
  int w0 = i0 + n0;
  if (t < nn) {
    int node = n0 + t;
    int base = w0 + (x - v) + t;          // excl scan + t self-loops before
    row_ptr[node] = base;
    eidx[base] = make_int2(node, __float_as_int(1.0f));  // self loop first
    cur[t] = base + 1;
  }
  if (b == 0 && t == 0) row_ptr[N] = ET;
  __syncthreads();
  for (int i = i0 + t; i < i1; i += 256) {
    int2 r = tmp[i];
    int pos = atomicAdd(&cur[(r.x >> 20) & (NPB - 1)], 1);
    eidx[pos] = make_int2(r.x & 0xFFFFF, r.y);
  }
}

// ---------------- node linear (LDS-tiled GEMM) ----------------
// [xl|xr] = h @ [Wl|Wr] + [bl|br]; xl stored as fp16 (gather table), xr fp32.

template<int CIN>
__global__ __launch_bounds__(256) void k_lin2_tiled(
    const float* __restrict__ h,
    const float* __restrict__ Wl, const float* __restrict__ bl,
    const float* __restrict__ Wr, const float* __restrict__ br,
    __half* __restrict__ xlh, float* __restrict__ xr, int N) {
  __shared__ float sW[64][128];  // 32 KB
  __shared__ float sH[64][64];   // 16 KB
  const int t = threadIdx.x;
  const int row0 = blockIdx.x * 64;
  const int c4 = (t & 31) * 4;
  const int rr = (t >> 5) * 8;

  float acc[8][4];
  #pragma unroll
  for (int r = 0; r < 8; r++)
    #pragma unroll
    for (int c = 0; c < 4; c++) acc[r][c] = 0.f;

  for (int kt = 0; kt < CIN; kt += 64) {
    __syncthreads();
    #pragma unroll
    for (int i = 0; i < 8; i++) {
      int flat = i * 1024 + t * 4;
      int k = flat >> 7, j = flat & 127;
      const float* Wsrc = (j < 64) ? Wl : Wr;
      *(float4*)&sW[k][j] = *(const float4*)&Wsrc[(size_t)(kt + k) * 64 + (j & 63)];
    }
    #pragma unroll
    for (int i = 0; i < 4; i++) {
      int flat = i * 1024 + t * 4;
      int r = flat >> 6, k = flat & 63;
      float4 v = make_float4(0.f, 0.f, 0.f, 0.f);
      if (row0 + r < N) v = *(const float4*)&h[(size_t)(row0 + r) * CIN + kt + k];
      *(float4*)&sH[r][k] = v;
    }
    __syncthreads();
    #pragma unroll 8
    for (int k = 0; k < 64; k++) {
      float4 w = *(float4*)&sW[k][c4];
      #pragma unroll
      for (int r = 0; r < 8; r++) {
        float hv = sH[rr + r][k];
        acc[r][0] = fmaf(hv, w.x, acc[r][0]);
        acc[r][1] = fmaf(hv, w.y, acc[r][1]);
        acc[r][2] = fmaf(hv, w.z, acc[r][2]);
        acc[r][3] = fmaf(hv, w.w, acc[r][3]);
      }
    }
  }

  const float* bsrc = (c4 < 64) ? bl : br;
  float bv[4];
  #pragma unroll
  for (int c = 0; c < 4; c++) bv[c] = bsrc[(c4 & 63) + c];
  #pragma unroll
  for (int r = 0; r < 8; r++) {
    int row = row0 + rr + r;
    if (row < N) {
      float v0 = acc[r][0] + bv[0], v1 = acc[r][1] + bv[1];
      float v2 = acc[r][2] + bv[2], v3 = acc[r][3] + bv[3];
      if (c4 < 64) {
        __half2 ha = __halves2half2(__float2half_rn(v0), __float2half_rn(v1));
        __half2 hb = __halves2half2(__float2half_rn(v2), __float2half_rn(v3));
        uint2 u;
        u.x = *(unsigned int*)&ha;
        u.y = *(unsigned int*)&hb;
        *(uint2*)&xlh[(size_t)row * 64 + c4] = u;
      } else {
        *(float4*)&xr[(size_t)row * 64 + (c4 & 63)] = make_float4(v0, v1, v2, v3);
      }
    }
  }
}

// ---------------- per-dst-node edge pass ----------------
// 4 groups per wave (16 lanes x 4 channels), fp16 gather, deferred-max
// online segment softmax, 2-deep prefetch pipeline per group.

#define RESCALE_THR 8.0f

__global__ __launch_bounds__(256) void k_gat_edge(
    const __half* __restrict__ xlh, const float* __restrict__ xr,
    const int* __restrict__ row_ptr, const int2* __restrict__ eidx,
    const float* __restrict__ We, const float* __restrict__ att,
    const float* __restrict__ bias,
    float* __restrict__ out, int N) {
  int n = (blockIdx.x * blockDim.x + threadIdx.x) >> 6;  // one wave per node
  if (n >= N) return;
  int lane = threadIdx.x & 63;
  int g = lane >> 4;
  int cb = (lane & 15) * 4;

  float4 xi = *(const float4*)&xr[(size_t)n * 64 + cb];
  float4 we = *(const float4*)&We[cb];
  float4 at = *(const float4*)&att[cb];

  int e0 = row_ptr[n], e1 = row_ptr[n + 1];

  float m = -INFINITY, s = 0.f;
  float4 acc = make_float4(0.f, 0.f, 0.f, 0.f);

  int e = e0 + g;
  int2 metaA = make_int2(0, 0), metaB = make_int2(0, 0);
  uint2 rawA = make_uint2(0, 0), rawB = make_uint2(0, 0);
  if (e < e1) {
    metaA = eidx[e];
    rawA = *(const uint2*)&xlh[(size_t)metaA.x * 64 + cb];
  }
  if (e + 4 < e1) {
    metaB = eidx[e + 4];
    rawB = *(const uint2*)&xlh[(size_t)metaB.x * 64 + cb];
  }

  while (e < e1) {
    int2 cm = metaA;
    uint2 craw = rawA;
    metaA = metaB;
    rawA = rawB;
    int en2 = e + 8;
    if (en2 < e1) {  // prefetch 2 iterations ahead
      metaB = eidx[en2];
      rawB = *(const uint2*)&xlh[(size_t)metaB.x * 64 + cb];
    }
    __half2 h01 = *(__half2*)&craw.x;
    __half2 h23 = *(__half2*)&craw.y;
    float x0 = __low2float(h01), x1 = __high2float(h01);
    float x2 = __low2float(h23), x3 = __high2float(h23);
    float eav = __int_as_float(cm.y);
    float z0 = xi.x + x0 + eav * we.x;
    float z1 = xi.y + x1 + eav * we.y;
    float z2 = xi.z + x2 + eav * we.z;
    float z3 = xi.w + x3 + eav * we.w;
    z0 = fmaxf(z0, 0.f) + 0.2f * fminf(z0, 0.f);
    z1 = fmaxf(z1, 0.f) + 0.2f * fminf(z1, 0.f);
    z2 = fmaxf(z2, 0.f) + 0.2f * fminf(z2, 0.f);
    z3 = fmaxf(z3, 0.f) + 0.2f * fminf(z3, 0.f);
    float p = z0 * at.x + z1 * at.y + z2 * at.z + z3 * at.w;
    #pragma unroll
    for (int off = 1; off < 16; off <<= 1) p += __shfl_xor(p, off, 64);
    // deferred-max online softmax: common path = 1 exp, no rescale
    if (p > m + RESCALE_THR) {
      float coef = __expf(m - p);  // 0 on first edge (m=-inf)
      s = fmaf(s, coef, 1.f);
      acc.x = fmaf(acc.x, coef, x0);
      acc.y = fmaf(acc.y, coef, x1);
      acc.z = fmaf(acc.z, coef, x2);
      acc.w = fmaf(acc.w, coef, x3);
      m = p;
    } else {
      float wgt = __expf(p - m);   // bounded by e^THR
      s += wgt;
      acc.x = fmaf(wgt, x0, acc.x);
      acc.y = fmaf(wgt, x1, acc.y);
      acc.z = fmaf(wgt, x2, acc.z);
      acc.w = fmaf(wgt, x3, acc.w);
    }
    e += 4;
  }

  // merge the 4 group states (lane^16/32 hold same channels)
  #pragma unroll
  for (int off = 16; off <= 32; off <<= 1) {
    float mo = __shfl_xor(m, off, 64);
    float so = __shfl_xor(s, off, 64);
    float4 ao;
    ao.x = __shfl_xor(acc.x, off, 64);
    ao.y = __shfl_xor(acc.y, off, 64);
    ao.z = __shfl_xor(acc.z, off, 64);
    ao.w = __shfl_xor(acc.w, off, 64);
    float mn = fmaxf(m, mo);
    float cs = (m == -INFINITY) ? 0.f : __expf(m - mn);
    float co = (mo == -INFINITY) ? 0.f : __expf(mo - mn);
    s = s * cs + so * co;
    acc.x = acc.x * cs + ao.x * co;
    acc.y = acc.y * cs + ao.y * co;
    acc.z = acc.z * cs + ao.z * co;
    acc.w = acc.w * cs + ao.w * co;
    m = mn;
  }

  if (g == 0) {
    float inv = 1.0f / s;
    float4 o;
    o.x = acc.x * inv + bias[cb + 0];
    o.y = acc.y * inv + bias[cb + 1];
    o.z = acc.z * inv + bias[cb + 2];
    o.w = acc.w * inv + bias[cb + 3];
    *(float4*)&out[(size_t)n * 64 + cb] = o;
  }
}

// ---------------- launch ----------------

extern "C" void kernel_launch(void* const* d_in, const int* in_sizes, int n_in,
                              void* d_out, int out_size, void* d_ws, size_t ws_size,
                              hipStream_t stream) {
  const float* x    = (const float*)d_in[0];
  const int*   ei   = (const int*)d_in[1];
  const float* ea   = (const float*)d_in[2];
  const float* Wl0  = (const float*)d_in[3];
  const float* bl0  = (const float*)d_in[4];
  const float* Wr0  = (const float*)d_in[5];
  const float* br0  = (const float*)d_in[6];
  const float* We0  = (const float*)d_in[7];
  const float* att0 = (const float*)d_in[8];
  const float* bias0= (const float*)d_in[9];
  const float* Wl1  = (const float*)d_in[10];
  const float* bl1  = (const float*)d_in[11];
  const float* Wr1  = (const float*)d_in[12];
  const float* br1  = (const float*)d_in[13];
  const float* We1  = (const float*)d_in[14];
  const float* att1 = (const float*)d_in[15];
  const float* bias1= (const float*)d_in[16];

  const int N  = in_sizes[0] / 128;
  const int E  = in_sizes[1] / 2;
  const int ET = E + N;
  const int* src = ei;
  const int* dst = ei + E;
  const int nbk = (N + NPB - 1) >> NPB_SHIFT;

  char* w = (char*)d_ws;
  __half* xlh    = (__half*)w; w += (size_t)N * 64 * 2;   // fp16 gather table
  float*  xr     = (float*)w;  w += (size_t)N * 64 * 4;
  float*  h1     = (float*)w;  w += (size_t)N * 64 * 4;
  int*    row_ptr= (int*)w;    w += (size_t)(N + 2) * 4;
  int2*   eidx   = (int2*)w;   w += (size_t)ET * 8;
  int*    bcount = (int*)w;    w += NBK_MAX * 4;
  int*    boff   = (int*)w;    w += (NBK_MAX + 1) * 4;
  int*    bcur   = (int*)w;    w += NBK_MAX * 4;
  // tmp aliases xlh+xr (19.2 MB >= E*8): CSR build precedes layer-0 lin2
  int2*   tmp    = (int2*)xlh;

  float* out = (float*)d_out;

  // ---- CSR build (bucket-local; same graph for both layers) ----
  {
    int nblk = 128;
    int chunk = (E + nblk - 1) / nblk;
    k_zero<<<(nbk + 255) / 256, 256, 0, stream>>>(bcount, nbk);
    k_bhist<<<nblk, 256, 0, stream>>>(dst, E, chunk, nbk, bcount);
    k_scan_buckets<<<1, NBK_MAX, 0, stream>>>(bcount, boff, bcur, nbk, E);
    k_scatter_agg<<<nblk, 256, 0, stream>>>(src, dst, ea, E, nbk, chunk, bcur, tmp);
    k_bucket_to_csr<<<nbk, 256, 0, stream>>>(tmp, boff, N, ET, eidx, row_ptr);
  }

  // ---- layer 0: 128 -> 64 ----
  {
    int nblk = (N + 63) / 64;
    k_lin2_tiled<128><<<nblk, 256, 0, stream>>>(x, Wl0, bl0, Wr0, br0, xlh, xr, N);
    k_gat_edge<<<(N + 3) / 4, 256, 0, stream>>>(xlh, xr, row_ptr, eidx, We0, att0, bias0, h1, N);
  }
  // ---- layer 1: 64 -> 64 ----
  {
    int nblk = (N + 63) / 64;
    k_lin2_tiled<64><<<nblk, 256, 0, stream>>>(h1, Wl1, bl1, Wr1, br1, xlh, xr, N);
    k_gat_edge<<<(N + 3) / 4, 256, 0, stream>>>(xlh, xr, row_ptr, eidx, We1, att1, bias1, out, N);
  }
}

// Round 9
// 199.525 us; speedup vs baseline: 1.3368x; 1.0200x over previous
//
#include <hip/hip_runtime.h>
#include <math.h>

// nodes-per-bucket = 128 (pow2). nbk = ceil(N/128) buckets (<= 512 for N<=65536).
#define NPB_SHIFT 7
#define NPB 128
#define NBK_MAX 512

typedef _Float16 f16x2 __attribute__((ext_vector_type(2)));
union F16U { f16x2 v; unsigned int u; };

// ---------------- CSR build (bucket-local) ----------------

__global__ void k_zero(int* p, int n) {
  int i = blockIdx.x * blockDim.x + threadIdx.x;
  if (i < n) p[i] = 0;
}

// bucket histogram of dst (LDS-aggregated)
__global__ __launch_bounds__(256) void k_bhist(
    const int* __restrict__ dst, int E, int chunk, int nbk, int* bcount) {
  __shared__ int bh[NBK_MAX];
  int t = threadIdx.x;
  for (int i = t; i < nbk; i += 256) bh[i] = 0;
  __syncthreads();
  int c0 = blockIdx.x * chunk;
  int c1 = min(E, c0 + chunk);
  for (int e = c0 + t; e < c1; e += 256)
    atomicAdd(&bh[dst[e] >> NPB_SHIFT], 1);
  __syncthreads();
  for (int i = t; i < nbk; i += 256)
    if (bh[i]) atomicAdd(&bcount[i], bh[i]);
}

// exclusive scan of bucket counts (single block, Hillis-Steele)
__global__ __launch_bounds__(NBK_MAX) void k_scan_buckets(
    const int* __restrict__ bcount, int* __restrict__ boff,
    int* __restrict__ bcur, int nbk, int E) {
  __shared__ int tmp[NBK_MAX];
  int t = threadIdx.x;
  int v = (t < nbk) ? bcount[t] : 0;
  int x = v;
  tmp[t] = x;
  __syncthreads();
  for (int off = 1; off < NBK_MAX; off <<= 1) {
    int y = (t >= off) ? tmp[t - off] : 0;
    __syncthreads();
    x += y;
    tmp[t] = x;
    __syncthreads();
  }
  if (t < nbk) {
    int excl = x - v;
    boff[t] = excl;
    bcur[t] = excl;
  }
  if (t == nbk - 1) boff[nbk] = E;
}

// P1: LDS-aggregated bucket scatter (count chunk, reserve run, place).
__global__ __launch_bounds__(256) void k_scatter_agg(
    const int* __restrict__ src, const int* __restrict__ dst,
    const float* __restrict__ ea, int E, int nbk, int chunk,
    int* bcur, int2* __restrict__ tmp) {
  __shared__ int lcnt[NBK_MAX], lcnt2[NBK_MAX], lbase[NBK_MAX];
  int t = threadIdx.x;
  for (int i = t; i < nbk; i += 256) { lcnt[i] = 0; lcnt2[i] = 0; }
  __syncthreads();
  int c0 = blockIdx.x * chunk;
  int c1 = min(E, c0 + chunk);
  for (int e = c0 + t; e < c1; e += 256)
    atomicAdd(&lcnt[dst[e] >> NPB_SHIFT], 1);
  __syncthreads();
  for (int i = t; i < nbk; i += 256) {
    int c = lcnt[i];
    lbase[i] = c ? atomicAdd(&bcur[i], c) : 0;
  }
  __syncthreads();
  for (int e = c0 + t; e < c1; e += 256) {
    int d = dst[e];
    int b = d >> NPB_SHIFT;
    int pos = lbase[b] + atomicAdd(&lcnt2[b], 1);
    tmp[pos] = make_int2(((d & (NPB - 1)) << 20) | src[e], __float_as_int(ea[e]));
  }
}

// P2: one block per bucket. Count per-node in LDS, scan, build row_ptr,
// write self-loops + place edges into the bucket's contiguous eidx window.
__global__ __launch_bounds__(256) void k_bucket_to_csr(
    const int2* __restrict__ tmp, const int* __restrict__ boff,
    int N, int ET, int2* __restrict__ eidx, int* __restrict__ row_ptr) {
  __shared__ int cnt[NPB], sc[NPB], cur[NPB];
  int b = blockIdx.x;
  int n0 = b << NPB_SHIFT;
  int nn = min(NPB, N - n0);
  int t = threadIdx.x;
  if (t < NPB) cnt[t] = 0;
  __syncthreads();
  int i0 = boff[b], i1 = boff[b + 1];
  for (int i = i0 + t; i < i1; i += 256)
    atomicAdd(&cnt[(tmp[i].x >> 20) & (NPB - 1)], 1);
  __syncthreads();
  int v = (t < NPB) ? cnt[t] : 0;
  int x = v;
  if (t < NPB) sc[t] = x;
  __syncthreads();
  for (int off = 1; off < NPB; off <<= 1) {
    int y = (t >= off && t < NPB) ? sc[t - off] : 0;
    __syncthreads();
    if (t < NPB) { x += y; sc[t] = x; }
    __syncthreads();
  }
  int w0 = i0 + n0;
  if (t < nn) {
    int node = n0 + t;
    int base = w0 + (x - v) + t;
    row_ptr[node] = base;
    eidx[base] = make_int2(node, __float_as_int(1.0f));  // self loop first
    cur[t] = base + 1;
  }
  if (b == 0 && t == 0) row_ptr[N] = ET;
  __syncthreads();
  for (int i = i0 + t; i < i1; i += 256) {
    int2 r = tmp[i];
    int pos = atomicAdd(&cur[(r.x >> 20) & (NPB - 1)], 1);
    eidx[pos] = make_int2(r.x & 0xFFFFF, r.y);
  }
}

// ---------------- node linear (LDS-tiled GEMM) ----------------
// [xl|xr] = h @ [Wl|Wr] + [bl|br]; BOTH tables stored fp16 for the edge pass.

template<int CIN>
__global__ __launch_bounds__(256) void k_lin2_tiled(
    const float* __restrict__ h,
    const float* __restrict__ Wl, const float* __restrict__ bl,
    const float* __restrict__ Wr, const float* __restrict__ br,
    _Float16* __restrict__ xlh, _Float16* __restrict__ xrh, int N) {
  __shared__ float sW[64][128];  // 32 KB
  __shared__ float sH[64][64];   // 16 KB
  const int t = threadIdx.x;
  const int row0 = blockIdx.x * 64;
  const int c4 = (t & 31) * 4;
  const int rr = (t >> 5) * 8;

  float acc[8][4];
  #pragma unroll
  for (int r = 0; r < 8; r++)
    #pragma unroll
    for (int c = 0; c < 4; c++) acc[r][c] = 0.f;

  for (int kt = 0; kt < CIN; kt += 64) {
    __syncthreads();
    #pragma unroll
    for (int i = 0; i < 8; i++) {
      int flat = i * 1024 + t * 4;
      int k = flat >> 7, j = flat & 127;
      const float* Wsrc = (j < 64) ? Wl : Wr;
      *(float4*)&sW[k][j] = *(const float4*)&Wsrc[(size_t)(kt + k) * 64 + (j & 63)];
    }
    #pragma unroll
    for (int i = 0; i < 4; i++) {
      int flat = i * 1024 + t * 4;
      int r = flat >> 6, k = flat & 63;
      float4 v = make_float4(0.f, 0.f, 0.f, 0.f);
      if (row0 + r < N) v = *(const float4*)&h[(size_t)(row0 + r) * CIN + kt + k];
      *(float4*)&sH[r][k] = v;
    }
    __syncthreads();
    #pragma unroll 8
    for (int k = 0; k < 64; k++) {
      float4 w = *(float4*)&sW[k][c4];
      #pragma unroll
      for (int r = 0; r < 8; r++) {
        float hv = sH[rr + r][k];
        acc[r][0] = fmaf(hv, w.x, acc[r][0]);
        acc[r][1] = fmaf(hv, w.y, acc[r][1]);
        acc[r][2] = fmaf(hv, w.z, acc[r][2]);
        acc[r][3] = fmaf(hv, w.w, acc[r][3]);
      }
    }
  }

  const float* bsrc = (c4 < 64) ? bl : br;
  float bv[4];
  #pragma unroll
  for (int c = 0; c < 4; c++) bv[c] = bsrc[(c4 & 63) + c];
  _Float16* o = (c4 < 64) ? xlh : xrh;
  #pragma unroll
  for (int r = 0; r < 8; r++) {
    int row = row0 + rr + r;
    if (row < N) {
      F16U ua, ub;
      ua.v = (f16x2){(_Float16)(acc[r][0] + bv[0]), (_Float16)(acc[r][1] + bv[1])};
      ub.v = (f16x2){(_Float16)(acc[r][2] + bv[2]), (_Float16)(acc[r][3] + bv[3])};
      *(uint2*)&o[(size_t)row * 64 + (c4 & 63)] = make_uint2(ua.u, ub.u);
    }
  }
}

// ---------------- per-dst-node edge pass ----------------
// 4 groups per wave (16 lanes x 4 channels), packed-fp16 math (v_pk_* +
// v_dot2_f32_f16), deferred-max online segment softmax, 2-deep prefetch.

#define RESCALE_THR 8.0f

__global__ __launch_bounds__(256) void k_gat_edge(
    const _Float16* __restrict__ xlh, const _Float16* __restrict__ xrh,
    const int* __restrict__ row_ptr, const int2* __restrict__ eidx,
    const float* __restrict__ We, const float* __restrict__ att,
    const float* __restrict__ bias,
    float* __restrict__ out, int N) {
  int n = (blockIdx.x * blockDim.x + threadIdx.x) >> 6;  // one wave per node
  if (n >= N) return;
  int lane = threadIdx.x & 63;
  int g = lane >> 4;
  int cb = (lane & 15) * 4;

  uint2 xiu = *(const uint2*)&xrh[(size_t)n * 64 + cb];
  F16U uxa, uxb; uxa.u = xiu.x; uxb.u = xiu.y;
  f16x2 xi01 = uxa.v, xi23 = uxb.v;
  float4 wef = *(const float4*)&We[cb];
  float4 atf = *(const float4*)&att[cb];
  f16x2 we01 = {(_Float16)wef.x, (_Float16)wef.y};
  f16x2 we23 = {(_Float16)wef.z, (_Float16)wef.w};
  f16x2 at01 = {(_Float16)atf.x, (_Float16)atf.y};
  f16x2 at23 = {(_Float16)atf.z, (_Float16)atf.w};
  const f16x2 zz  = {(_Float16)0.f, (_Float16)0.f};
  const f16x2 c02 = {(_Float16)0.2f, (_Float16)0.2f};

  int e0 = row_ptr[n], e1 = row_ptr[n + 1];

  float m = -INFINITY, s = 0.f;
  float4 acc = make_float4(0.f, 0.f, 0.f, 0.f);

  int e = e0 + g;
  int2 metaA = make_int2(0, 0), metaB = make_int2(0, 0);
  uint2 rawA = make_uint2(0, 0), rawB = make_uint2(0, 0);
  if (e < e1) {
    metaA = eidx[e];
    rawA = *(const uint2*)&xlh[(size_t)metaA.x * 64 + cb];
  }
  if (e + 4 < e1) {
    metaB = eidx[e + 4];
    rawB = *(const uint2*)&xlh[(size_t)metaB.x * 64 + cb];
  }

  while (e < e1) {
    int2 cm = metaA;
    uint2 craw = rawA;
    metaA = metaB;
    rawA = rawB;
    int en2 = e + 8;
    if (en2 < e1) {  // prefetch 2 iterations ahead
      metaB = eidx[en2];
      rawB = *(const uint2*)&xlh[(size_t)metaB.x * 64 + cb];
    }
    F16U u0, u1; u0.u = craw.x; u1.u = craw.y;
    f16x2 xj01 = u0.v, xj23 = u1.v;
    float eav = __int_as_float(cm.y);
    _Float16 eah = (_Float16)eav;
    f16x2 ea2 = {eah, eah};
    // z = leaky_relu(xi + xj + ea*We) in packed fp16
    f16x2 z01 = __builtin_elementwise_fma(ea2, we01, xi01 + xj01);
    f16x2 z23 = __builtin_elementwise_fma(ea2, we23, xi23 + xj23);
    f16x2 l01 = __builtin_elementwise_fma(
        c02, __builtin_elementwise_min(z01, zz), __builtin_elementwise_max(z01, zz));
    f16x2 l23 = __builtin_elementwise_fma(
        c02, __builtin_elementwise_min(z23, zz), __builtin_elementwise_max(z23, zz));
    // logit partial via v_dot2_f32_f16 (f32 accumulate)
    float p = __builtin_amdgcn_fdot2(l01, at01,
              __builtin_amdgcn_fdot2(l23, at23, 0.f, false), false);
    #pragma unroll
    for (int off = 1; off < 16; off <<= 1) p += __shfl_xor(p, off, 64);
    // deferred-max online softmax: common path = 1 exp, no rescale
    if (p > m + RESCALE_THR) {
      float coef = __expf(m - p);  // 0 on first edge (m=-inf)
      s = fmaf(s, coef, 1.f);
      acc.x = fmaf(acc.x, coef, (float)xj01[0]);
      acc.y = fmaf(acc.y, coef, (float)xj01[1]);
      acc.z = fmaf(acc.z, coef, (float)xj23[0]);
      acc.w = fmaf(acc.w, coef, (float)xj23[1]);
      m = p;
    } else {
      float wgt = __expf(p - m);   // bounded by e^THR
      s += wgt;
      acc.x = fmaf(wgt, (float)xj01[0], acc.x);
      acc.y = fmaf(wgt, (float)xj01[1], acc.y);
      acc.z = fmaf(wgt, (float)xj23[0], acc.z);
      acc.w = fmaf(wgt, (float)xj23[1], acc.w);
    }
    e += 4;
  }

  // merge the 4 group states (lane^16/32 hold same channels)
  #pragma unroll
  for (int off = 16; off <= 32; off <<= 1) {
    float mo = __shfl_xor(m, off, 64);
    float so = __shfl_xor(s, off, 64);
    float4 ao;
    ao.x = __shfl_xor(acc.x, off, 64);
    ao.y = __shfl_xor(acc.y, off, 64);
    ao.z = __shfl_xor(acc.z, off, 64);
    ao.w = __shfl_xor(acc.w, off, 64);
    float mn = fmaxf(m, mo);
    float cs = (m == -INFINITY) ? 0.f : __expf(m - mn);
    float co = (mo == -INFINITY) ? 0.f : __expf(mo - mn);
    s = s * cs + so * co;
    acc.x = acc.x * cs + ao.x * co;
    acc.y = acc.y * cs + ao.y * co;
    acc.z = acc.z * cs + ao.z * co;
    acc.w = acc.w * cs + ao.w * co;
    m = mn;
  }

  if (g == 0) {
    float inv = 1.0f / s;
    float4 o;
    o.x = acc.x * inv + bias[cb + 0];
    o.y = acc.y * inv + bias[cb + 1];
    o.z = acc.z * inv + bias[cb + 2];
    o.w = acc.w * inv + bias[cb + 3];
    *(float4*)&out[(size_t)n * 64 + cb] = o;
  }
}

// ---------------- launch ----------------

extern "C" void kernel_launch(void* const* d_in, const int* in_sizes, int n_in,
                              void* d_out, int out_size, void* d_ws, size_t ws_size,
                              hipStream_t stream) {
  const float* x    = (const float*)d_in[0];
  const int*   ei   = (const int*)d_in[1];
  const float* ea   = (const float*)d_in[2];
  const float* Wl0  = (const float*)d_in[3];
  const float* bl0  = (const float*)d_in[4];
  const float* Wr0  = (const float*)d_in[5];
  const float* br0  = (const float*)d_in[6];
  const float* We0  = (const float*)d_in[7];
  const float* att0 = (const float*)d_in[8];
  const float* bias0= (const float*)d_in[9];
  const float* Wl1  = (const float*)d_in[10];
  const float* bl1  = (const float*)d_in[11];
  const float* Wr1  = (const float*)d_in[12];
  const float* br1  = (const float*)d_in[13];
  const float* We1  = (const float*)d_in[14];
  const float* att1 = (const float*)d_in[15];
  const float* bias1= (const float*)d_in[16];

  const int N  = in_sizes[0] / 128;
  const int E  = in_sizes[1] / 2;
  const int ET = E + N;
  const int* src = ei;
  const int* dst = ei + E;
  const int nbk = (N + NPB - 1) >> NPB_SHIFT;

  char* w = (char*)d_ws;
  _Float16* xlh  = (_Float16*)w; w += (size_t)N * 64 * 2;  // fp16 gather table (src side)
  _Float16* xrh  = (_Float16*)w; w += (size_t)N * 64 * 2;  // fp16 table (dst side)
  float*  h1     = (float*)w;  w += (size_t)N * 64 * 4;
  int*    row_ptr= (int*)w;    w += (size_t)(N + 2) * 4;
  int2*   eidx   = (int2*)w;   w += (size_t)ET * 8;
  int*    bcount = (int*)w;    w += NBK_MAX * 4;
  int*    boff   = (int*)w;    w += (NBK_MAX + 1) * 4;
  int*    bcur   = (int*)w;    w += NBK_MAX * 4;
  // tmp aliases xlh+xrh (12.8 MB >= E*8): CSR build precedes layer-0 lin2
  int2*   tmp    = (int2*)xlh;

  float* out = (float*)d_out;

  // ---- CSR build (bucket-local; same graph for both layers) ----
  {
    int nblk = 128;
    int chunk = (E + nblk - 1) / nblk;
    k_zero<<<(nbk + 255) / 256, 256, 0, stream>>>(bcount, nbk);
    k_bhist<<<nblk, 256, 0, stream>>>(dst, E, chunk, nbk, bcount);
    k_scan_buckets<<<1, NBK_MAX, 0, stream>>>(bcount, boff, bcur, nbk, E);
    k_scatter_agg<<<nblk, 256, 0, stream>>>(src, dst, ea, E, nbk, chunk, bcur, tmp);
    k_bucket_to_csr<<<nbk, 256, 0, stream>>>(tmp, boff, N, ET, eidx, row_ptr);
  }

  // ---- layer 0: 128 -> 64 ----
  {
    int nblk = (N + 63) / 64;
    k_lin2_tiled<128><<<nblk, 256, 0, stream>>>(x, Wl0, bl0, Wr0, br0, xlh, xrh, N);
    k_gat_edge<<<(N + 3) / 4, 256, 0, stream>>>(xlh, xrh, row_ptr, eidx, We0, att0, bias0, h1, N);
  }
  // ---- layer 1: 64 -> 64 ----
  {
    int nblk = (N + 63) / 64;
    k_lin2_tiled<64><<<nblk, 256, 0, stream>>>(h1, Wl1, bl1, Wr1, br1, xlh, xrh, N);
    k_gat_edge<<<(N + 3) / 4, 256, 0, stream>>>(xlh, xrh, row_ptr, eidx, We1, att1, bias1, out, N);
  }
}